// Round 15
// baseline (335.630 us; speedup 1.0000x reference)
//
#include <hip/hip_runtime.h>

// Luong 'general' attention, B=4 D=256 L=4096.
// K0 transpose/cast q,c -> [B][L][D] f16 (+ fused cD16 [B][D][L] f16 cast);
// K0b W f32->f16 ; K1 linear qw=q@W^T+b.
// K2a attn_lsum: STANDALONE row-sum kernel — 1024 blocks, 4 blocks/CU, no LDS
//     staging, no per-tile barriers; scores streamed from L2-resident cT16
//     (bit-identical MFMA sequence to K2b) -> lsum_ws[b][qh][o]. This replaces
//     r9's in-kernel phase A (~85us of lockstep barriers).
// K2b attn_pv: r9's proven phase B verbatim (256 blocks lockstep, 512 thr):
//     scores A from DMA-staged c_lds (dbuf), w=exp(s)*invl -> f32x4 wgt +
//     f16x4 wbuf; PV A=wbuf b128, B direct from L2-hot cD16; invl from lsum_ws.
// LDS (pv): 2x32KB c_lds + 8KB wbuf = 72 KB (obuf aliases smem[0]).

#define BATCH 4
#define DDIM  256
#define LSEQ  4096
#define TQ    64

typedef float    f32x4 __attribute__((ext_vector_type(4)));
typedef _Float16 f16x8 __attribute__((ext_vector_type(8)));
typedef _Float16 f16x4 __attribute__((ext_vector_type(4)));

__device__ __forceinline__ void gld16(const void* g, void* l) {
  __builtin_amdgcn_global_load_lds((const __attribute__((address_space(1))) void*)g,
                                   (__attribute__((address_space(3))) void*)l, 16, 0, 0);
}

// ---------------- K0: [B][D][L] f32 -> [B][L][D] f16 (+ cD16 for context) ---
__global__ __launch_bounds__(256) void transpose_cast(
    const float* __restrict__ q_in, const float* __restrict__ c_in,
    _Float16* __restrict__ q_out, _Float16* __restrict__ c_out,
    _Float16* __restrict__ cD16)
{
  __shared__ float tile[64][68];
  const int which = blockIdx.z >> 2;
  const int b     = blockIdx.z & 3;
  const float* __restrict__ src = which ? c_in : q_in;
  _Float16* __restrict__ dst    = which ? c_out : q_out;
  const int l0 = blockIdx.x * 64, d0 = blockIdx.y * 64;
  const int tid = threadIdx.x;
  const int tr = tid >> 4, tc = (tid & 15) << 2;
#pragma unroll
  for (int i = 0; i < 4; ++i) {
    int d = tr + i * 16;
    f32x4 v = *(const f32x4*)(src + ((size_t)b * DDIM + d0 + d) * LSEQ + l0 + tc);
    *(f32x4*)&tile[d][tc] = v;
    if (which) {
      f16x4 h;
      h[0] = (_Float16)v[0]; h[1] = (_Float16)v[1];
      h[2] = (_Float16)v[2]; h[3] = (_Float16)v[3];
      *(f16x4*)(cD16 + ((size_t)b * DDIM + d0 + d) * LSEQ + l0 + tc) = h;
    }
  }
  __syncthreads();
#pragma unroll
  for (int i = 0; i < 4; ++i) {
    int l = tr + i * 16;
    f16x4 h;
    h[0] = (_Float16)tile[tc + 0][l];
    h[1] = (_Float16)tile[tc + 1][l];
    h[2] = (_Float16)tile[tc + 2][l];
    h[3] = (_Float16)tile[tc + 3][l];
    *(f16x4*)(dst + ((size_t)b * LSEQ + l0 + l) * DDIM + d0 + tc) = h;
  }
}

// ---------------- K0b: W f32 -> f16 -----------------------------------------
__global__ __launch_bounds__(256) void wconv(const float* __restrict__ w,
                                             _Float16* __restrict__ w16) {
  int i = (blockIdx.x * 256 + threadIdx.x) * 4;
  f32x4 v = *(const f32x4*)(w + i);
  f16x4 h;
  h[0] = (_Float16)v[0]; h[1] = (_Float16)v[1];
  h[2] = (_Float16)v[2]; h[3] = (_Float16)v[3];
  *(f16x4*)(w16 + i) = h;
}

// ---------------- K1: qw16 = qT16 @ W^T + bias ------------------------------
__global__ __launch_bounds__(256) void linear_q(
    const _Float16* __restrict__ qT16, const _Float16* __restrict__ W16,
    const float* __restrict__ bias, _Float16* __restrict__ qw16)
{
  const int tid = threadIdx.x;
  const int wv = tid >> 6, ln = tid & 63, g = ln >> 4, c16 = ln & 15;
  const size_t r0 = (size_t)blockIdx.x * 64 + wv * 16;

  f16x8 qa[8];
  const _Float16* qrow = qT16 + (r0 + c16) * DDIM + g * 8;
#pragma unroll
  for (int kk = 0; kk < 8; ++kk) qa[kk] = *(const f16x8*)(qrow + kk * 32);

  f32x4 acc[16];
#pragma unroll
  for (int n = 0; n < 16; ++n) acc[n] = f32x4{0.f, 0.f, 0.f, 0.f};

#pragma unroll 2
  for (int kk = 0; kk < 8; ++kk) {
#pragma unroll
    for (int n = 0; n < 16; ++n) {
      f16x8 bf = *(const f16x8*)(W16 + (n * 16 + c16) * DDIM + kk * 32 + g * 8);
      acc[n] = __builtin_amdgcn_mfma_f32_16x16x32_f16(qa[kk], bf, acc[n], 0, 0, 0);
    }
  }
#pragma unroll
  for (int n = 0; n < 16; ++n) {
    float bb = bias[n * 16 + c16];
#pragma unroll
    for (int r = 0; r < 4; ++r)
      qw16[(r0 + 4 * g + r) * DDIM + n * 16 + c16] = (_Float16)(acc[n][r] + bb);
  }
}

// ---------------- K2a: row sums of exp(scores) ------------------------------
// 1024 blocks: (otA 0..127 -> 32 o) x (qh 0..1 -> 32 tiles) x batch.
// 4 waves (qw = q-frag). No staging: A-frags direct from L2-resident cT16.
__global__ __launch_bounds__(256, 4) void attn_lsum(
    const _Float16* __restrict__ qw16,
    const _Float16* __restrict__ cT16,
    float* __restrict__ lsum_ws)
{
  __shared__ float red[4][32];
  const int tid = threadIdx.x;
  const int qw  = tid >> 6;
  const int ln  = tid & 63;
  const int g   = ln >> 4;
  const int c16 = ln & 15;

  const int lin = blockIdx.x;
  const int b   = (lin & 7) >> 1;
  const int r2  = ((lin >> 3) << 1) | (lin & 1);  // 0..255
  const int otA = r2 >> 1;                        // 0..127
  const int qh  = r2 & 1;
  const int o0  = otA * 32;

  const _Float16* __restrict__ cbase = cT16 + (size_t)b * LSEQ * DDIM;

  f16x8 qb[2][8];
#pragma unroll
  for (int of = 0; of < 2; ++of)
#pragma unroll
    for (int kk = 0; kk < 8; ++kk)
      qb[of][kk] = *(const f16x8*)(qw16 +
          ((size_t)(b * LSEQ + o0 + of * 16 + c16) << 8) + kk * 32 + g * 8);

  float lsum0 = 0.f, lsum1 = 0.f;
  for (int t = 0; t < 32; ++t) {
    const int tq = qh * 32 + t;
    f16x8 aa[8];
    const _Float16* src = cbase + ((size_t)(tq * TQ + qw * 16 + c16) << 8) + g * 8;
#pragma unroll
    for (int kk = 0; kk < 8; ++kk) aa[kk] = *(const f16x8*)(src + kk * 32);
    f32x4 s0{0.f, 0.f, 0.f, 0.f}, s1{0.f, 0.f, 0.f, 0.f};
#pragma unroll
    for (int kk = 0; kk < 8; ++kk) {
      s0 = __builtin_amdgcn_mfma_f32_16x16x32_f16(aa[kk], qb[0][kk], s0, 0, 0, 0);
      s1 = __builtin_amdgcn_mfma_f32_16x16x32_f16(aa[kk], qb[1][kk], s1, 0, 0, 0);
    }
#pragma unroll
    for (int r = 0; r < 4; ++r) {
      lsum0 += __expf(s0[r]);
      lsum1 += __expf(s1[r]);
    }
  }
  lsum0 += __shfl_xor(lsum0, 16); lsum0 += __shfl_xor(lsum0, 32);
  lsum1 += __shfl_xor(lsum1, 16); lsum1 += __shfl_xor(lsum1, 32);
  if (ln < 16) {
    red[qw][ln]      = lsum0;
    red[qw][16 + ln] = lsum1;
  }
  __syncthreads();
  if (tid < 32)
    lsum_ws[((size_t)(b * 2 + qh)) * LSEQ + o0 + tid] =
        red[0][tid] + red[1][tid] + red[2][tid] + red[3][tid];
}

// ---------------- K2b: weights + PV (r9 phase B, lockstep 256 blocks) -------
// c_lds (q-major): byte = q*512 + d*2 ^ ((q&7)<<4); scores-A read b128:
//   off=(qw*16+c16)*512+kk*64+g*16 ^ ((c16&7)<<4).
// wbuf [64 o][64 q]: byte = o*128 + q*2 ^ ((o&7)<<4); write f16x4, read b128.
__global__ __launch_bounds__(512) void attn_pv(
    const _Float16* __restrict__ qw16,
    const _Float16* __restrict__ cT16,
    const _Float16* __restrict__ cD16,
    const float* __restrict__ lsum_ws,
    float* __restrict__ outp,
    float* __restrict__ wgt)
{
  __shared__ __align__(16) char smem[2][32768];  // c_lds double buffer
  __shared__ __align__(16) char wbuf[8192];      // w tile [64 o][64 q] f16 swz
  char* obuf = &smem[0][0];                      // epilogue alias (64KB, dead)

  const int tid = threadIdx.x;
  const int wv  = tid >> 6;       // 0..7
  const int qw  = wv & 3;         // scores q-frag / PV d-slice
  const int oh  = wv >> 2;        // scores o-half / PV k-half
  const int ln  = tid & 63;
  const int g   = ln >> 4;
  const int c16 = ln & 15;

  // batch -> XCD-pair remap (context 2MB/batch stays L2-resident under lockstep)
  const int lin   = blockIdx.y * 64 + blockIdx.x;
  const int b     = (lin & 7) >> 1;
  const int otile = ((lin >> 3) << 1) | (lin & 1);
  const int o0    = otile * 64;
  const int bo    = b * LSEQ + o0;

  const _Float16* __restrict__ cbase = cT16 + (size_t)b * LSEQ * DDIM;
  const _Float16* __restrict__ cDb   = cD16 + (size_t)b * DDIM * LSEQ;

  // invl from the two q-half partial sums
  float invl[2];
#pragma unroll
  for (int of = 0; of < 2; ++of) {
    int o = o0 + oh * 32 + of * 16 + c16;
    invl[of] = 1.0f / (lsum_ws[(size_t)(b * 2) * LSEQ + o] +
                       lsum_ws[(size_t)(b * 2 + 1) * LSEQ + o]);
  }

  // B-frags (qw rows as B operand): o = oh*32 + of*16 + c16, k = kk*32+g*8..
  f16x8 qb[2][8];
#pragma unroll
  for (int of = 0; of < 2; ++of)
#pragma unroll
    for (int kk = 0; kk < 8; ++kk)
      qb[of][kk] = *(const f16x8*)(qw16 +
          ((size_t)(bo + oh * 32 + of * 16 + c16) << 8) + kk * 32 + g * 8);

  auto issue_dma = [&](int t, int pp) {
#pragma unroll
    for (int i = 0; i < 4; ++i) {
      unsigned x  = (unsigned)tid * 16 + i * 8192;
      unsigned q  = x >> 9;
      unsigned db = (x & 511u) ^ ((q & 7u) << 4);
      gld16(cbase + ((size_t)(t * TQ + q) << 8) + (db >> 1), &smem[pp][x]);
    }
  };

  f32x4 oacc[4][4];
#pragma unroll
  for (int m = 0; m < 4; ++m)
#pragma unroll
    for (int nf = 0; nf < 4; ++nf) oacc[m][nf] = f32x4{0.f, 0.f, 0.f, 0.f};

  int p = 0;
  issue_dma(0, 0);
  for (int t = 0; t < LSEQ / TQ; ++t) {
    const int q0 = t * TQ;
    if (t == 0) asm volatile("s_waitcnt vmcnt(0)" ::: "memory");
    else        asm volatile("s_waitcnt vmcnt(2)" ::: "memory");
    __builtin_amdgcn_s_barrier();
    __builtin_amdgcn_sched_barrier(0);

    // PV B-frags for this tile, direct from L2-hot cD16
    f16x8 bv[4];
#pragma unroll
    for (int nf = 0; nf < 4; ++nf)
      bv[nf] = *(const f16x8*)(cDb +
          ((size_t)(qw * 64 + nf * 16 + c16) << 12) + q0 + oh * 32 + g * 8);

    if (t < LSEQ / TQ - 1) issue_dma(t + 1, p ^ 1);

    const char* cl = smem[p];
    f32x4 sa0{0.f, 0.f, 0.f, 0.f}, sa1{0.f, 0.f, 0.f, 0.f};
#pragma unroll
    for (int kk = 0; kk < 8; ++kk) {
      unsigned off = (unsigned)((qw * 16 + c16) * 512 + kk * 64 + g * 16) ^
                     ((unsigned)(c16 & 7) << 4);
      f16x8 af = *(const f16x8*)(cl + off);
      sa0 = __builtin_amdgcn_mfma_f32_16x16x32_f16(af, qb[0][kk], sa0, 0, 0, 0);
      sa1 = __builtin_amdgcn_mfma_f32_16x16x32_f16(af, qb[1][kk], sa1, 0, 0, 0);
    }

    // weights: lane holds o = oh*32+of*16+c16, q = q0+qw*16+4g+r (contig r)
#pragma unroll
    for (int of = 0; of < 2; ++of) {
      f32x4 sv = of ? sa1 : sa0;
      f32x4 wv4;
      f16x4 wh;
#pragma unroll
      for (int r = 0; r < 4; ++r) {
        float w = __expf(sv[r]) * invl[of];
        wv4[r] = w;
        wh[r]  = (_Float16)w;
      }
      int o = oh * 32 + of * 16 + c16;
      *(f32x4*)(wgt + ((size_t)(bo + o) << 12) + q0 + qw * 16 + 4 * g) = wv4;
      unsigned wb = (unsigned)(o * 128 + qw * 32 + g * 8) ^ ((unsigned)(o & 7) << 4);
      *(f16x4*)(wbuf + wb) = wh;
    }
    asm volatile("s_waitcnt lgkmcnt(0)" ::: "memory");
    __builtin_amdgcn_s_barrier();
    __builtin_amdgcn_sched_barrier(0);

    // PV: A = wbuf rows (o), k = q-half oh; B = bv; out d-slice qw
#pragma unroll
    for (int m = 0; m < 4; ++m) {
      unsigned off = (unsigned)((m * 16 + c16) * 128 + oh * 64 + g * 16) ^
                     ((unsigned)(c16 & 7) << 4);
      f16x8 wa = *(const f16x8*)(wbuf + off);
#pragma unroll
      for (int nf = 0; nf < 4; ++nf)
        oacc[m][nf] =
            __builtin_amdgcn_mfma_f32_16x16x32_f16(wa, bv[nf], oacc[m][nf], 0, 0, 0);
    }
    p ^= 1;
  }

  // ---- cross-oh reduction via obuf (smem dead), then store out
  __syncthreads();
  if (oh == 1) {
#pragma unroll
    for (int m = 0; m < 4; ++m)
#pragma unroll
      for (int nf = 0; nf < 4; ++nf)
        *(f32x4*)(obuf + qw * 16384 + (m * 4 + nf) * 1024 + ln * 16) = oacc[m][nf];
  }
  __syncthreads();
  if (oh == 0) {
#pragma unroll
    for (int m = 0; m < 4; ++m)
#pragma unroll
      for (int nf = 0; nf < 4; ++nf) {
        f32x4 o2 = *(const f32x4*)(obuf + qw * 16384 + (m * 4 + nf) * 1024 + ln * 16);
        f32x4 o  = oacc[m][nf] + o2;
#pragma unroll
        for (int r = 0; r < 4; ++r)
          outp[((size_t)(bo + m * 16 + 4 * g + r) << 8) + qw * 64 + nf * 16 + c16] = o[r];
      }
  }
}

extern "C" void kernel_launch(void* const* d_in, const int* in_sizes, int n_in,
                              void* d_out, int out_size, void* d_ws, size_t ws_size,
                              hipStream_t stream) {
  const float* query   = (const float*)d_in[0];
  const float* context = (const float*)d_in[1];
  const float* W_in    = (const float*)d_in[2];
  const float* b_in    = (const float*)d_in[3];

  float* outp = (float*)d_out;
  float* wgt  = outp + (size_t)BATCH * LSEQ * DDIM;  // outputs concat: out, weights

  const size_t NELEM = (size_t)BATCH * LSEQ * DDIM;  // 4,194,304
  _Float16* qT16 = (_Float16*)d_ws;
  _Float16* cT16 = qT16 + NELEM;
  _Float16* qw16 = cT16 + NELEM;
  _Float16* W16  = qw16 + NELEM;             // +65536 halfs
  float*    lsum_ws = (float*)(W16 + 65536); // 2*B*L f32 = 128 KB
  _Float16* cD16 = (_Float16*)(lsum_ws + 2 * BATCH * LSEQ);  // ~33.8 MB total

  transpose_cast<<<dim3(LSEQ / 64, DDIM / 64, 2 * BATCH), 256, 0, stream>>>(
      query, context, qT16, cT16, cD16);
  wconv<<<(DDIM * DDIM) / 1024, 256, 0, stream>>>(W_in, W16);
  linear_q<<<(BATCH * LSEQ) / 64, 256, 0, stream>>>(qT16, W16, b_in, qw16);
  attn_lsum<<<1024, 256, 0, stream>>>(qw16, cT16, lsum_ws);
  attn_pv<<<dim3(64, BATCH), 512, 0, stream>>>(qw16, cT16, cD16, lsum_ws, outp, wgt);
}

// Round 16
// 292.619 us; speedup vs baseline: 1.1470x; 1.1470x over previous
//
#include <hip/hip_runtime.h>

// Luong 'general' attention, B=4 D=256 L=4096.
// K0 transpose/cast q,c -> [B][L][D] f16 (+ fused cD16 [B][D][L] f16 cast);
// K0b W f32->f16 ; K1 linear qw=q@W^T+b.
// K2 attn_main: r10 base (256 blocks lockstep, 1024 thr = 16 waves, TQ=64,
//   attn 216us) + SOFTWARE-PIPELINED phase B: scores(t+1) ∥ PV(t) share one
//   barrier interval (independent: scores reads c_lds[p^1], PV reads wbuf(t));
//   thin interval holds only exp+stores. Same 2 barriers/iter, PV 1 tile late.
//   phase A unchanged: staged scores, lsum += exp(s).
// LDS: 2x32KB c_lds + 8KB wbuf + 1KB redbuf = 74 KB (obuf aliases smem[0]).

#define BATCH 4
#define DDIM  256
#define LSEQ  4096
#define TQ    64

typedef float    f32x4 __attribute__((ext_vector_type(4)));
typedef _Float16 f16x8 __attribute__((ext_vector_type(8)));
typedef _Float16 f16x4 __attribute__((ext_vector_type(4)));

__device__ __forceinline__ void gld16(const void* g, void* l) {
  __builtin_amdgcn_global_load_lds((const __attribute__((address_space(1))) void*)g,
                                   (__attribute__((address_space(3))) void*)l, 16, 0, 0);
}

// ---------------- K0: [B][D][L] f32 -> [B][L][D] f16 (+ cD16 for context) ---
__global__ __launch_bounds__(256) void transpose_cast(
    const float* __restrict__ q_in, const float* __restrict__ c_in,
    _Float16* __restrict__ q_out, _Float16* __restrict__ c_out,
    _Float16* __restrict__ cD16)
{
  __shared__ float tile[64][68];
  const int which = blockIdx.z >> 2;
  const int b     = blockIdx.z & 3;
  const float* __restrict__ src = which ? c_in : q_in;
  _Float16* __restrict__ dst    = which ? c_out : q_out;
  const int l0 = blockIdx.x * 64, d0 = blockIdx.y * 64;
  const int tid = threadIdx.x;
  const int tr = tid >> 4, tc = (tid & 15) << 2;
#pragma unroll
  for (int i = 0; i < 4; ++i) {
    int d = tr + i * 16;
    f32x4 v = *(const f32x4*)(src + ((size_t)b * DDIM + d0 + d) * LSEQ + l0 + tc);
    *(f32x4*)&tile[d][tc] = v;
    if (which) {
      f16x4 h;
      h[0] = (_Float16)v[0]; h[1] = (_Float16)v[1];
      h[2] = (_Float16)v[2]; h[3] = (_Float16)v[3];
      *(f16x4*)(cD16 + ((size_t)b * DDIM + d0 + d) * LSEQ + l0 + tc) = h;
    }
  }
  __syncthreads();
#pragma unroll
  for (int i = 0; i < 4; ++i) {
    int l = tr + i * 16;
    f16x4 h;
    h[0] = (_Float16)tile[tc + 0][l];
    h[1] = (_Float16)tile[tc + 1][l];
    h[2] = (_Float16)tile[tc + 2][l];
    h[3] = (_Float16)tile[tc + 3][l];
    *(f16x4*)(dst + ((size_t)b * LSEQ + l0 + l) * DDIM + d0 + tc) = h;
  }
}

// ---------------- K0b: W f32 -> f16 -----------------------------------------
__global__ __launch_bounds__(256) void wconv(const float* __restrict__ w,
                                             _Float16* __restrict__ w16) {
  int i = (blockIdx.x * 256 + threadIdx.x) * 4;
  f32x4 v = *(const f32x4*)(w + i);
  f16x4 h;
  h[0] = (_Float16)v[0]; h[1] = (_Float16)v[1];
  h[2] = (_Float16)v[2]; h[3] = (_Float16)v[3];
  *(f16x4*)(w16 + i) = h;
}

// ---------------- K1: qw16 = qT16 @ W^T + bias ------------------------------
__global__ __launch_bounds__(256) void linear_q(
    const _Float16* __restrict__ qT16, const _Float16* __restrict__ W16,
    const float* __restrict__ bias, _Float16* __restrict__ qw16)
{
  const int tid = threadIdx.x;
  const int wv = tid >> 6, ln = tid & 63, g = ln >> 4, c16 = ln & 15;
  const size_t r0 = (size_t)blockIdx.x * 64 + wv * 16;

  f16x8 qa[8];
  const _Float16* qrow = qT16 + (r0 + c16) * DDIM + g * 8;
#pragma unroll
  for (int kk = 0; kk < 8; ++kk) qa[kk] = *(const f16x8*)(qrow + kk * 32);

  f32x4 acc[16];
#pragma unroll
  for (int n = 0; n < 16; ++n) acc[n] = f32x4{0.f, 0.f, 0.f, 0.f};

#pragma unroll 2
  for (int kk = 0; kk < 8; ++kk) {
#pragma unroll
    for (int n = 0; n < 16; ++n) {
      f16x8 bf = *(const f16x8*)(W16 + (n * 16 + c16) * DDIM + kk * 32 + g * 8);
      acc[n] = __builtin_amdgcn_mfma_f32_16x16x32_f16(qa[kk], bf, acc[n], 0, 0, 0);
    }
  }
#pragma unroll
  for (int n = 0; n < 16; ++n) {
    float bb = bias[n * 16 + c16];
#pragma unroll
    for (int r = 0; r < 4; ++r)
      qw16[(r0 + 4 * g + r) * DDIM + n * 16 + c16] = (_Float16)(acc[n][r] + bb);
  }
}

// ---------------- K2: fused attention (16 waves, pipelined phase B) ---------
// c_lds (q-major): byte = q*512 + d*2 ^ ((q&7)<<4); scores-A read b128:
//   off=(qw*16+c16)*512+kk*64+g*16 ^ ((c16&7)<<4).
// wbuf [64 o][64 q]: byte = o*128 + q*2 ^ ((o&7)<<4); write f16x4, read b128.
// DMA: linear LDS dest + inverse-swizzled global source (rule #21).
__global__ __launch_bounds__(1024, 4) void attn_main(
    const _Float16* __restrict__ qw16,
    const _Float16* __restrict__ cT16,
    const _Float16* __restrict__ cD16,
    float* __restrict__ outp,
    float* __restrict__ wgt)
{
  __shared__ __align__(16) char smem[2][32768];  // c_lds double buffer
  __shared__ __align__(16) char wbuf[8192];      // w tile [64 o][64 q] f16 swz
  __shared__ float redbuf[4][64];                // per-qw row sums
  char* obuf = &smem[0][0];                      // epilogue alias (64KB, dead)

  const int tid = threadIdx.x;
  const int wv  = tid >> 6;       // 0..15
  const int qw  = wv & 3;         // scores q-frag
  const int ow  = wv >> 2;        // scores o-frag (16 o each)
  const int kh  = wv & 1;         // PV k-half (32 q)
  const int dw  = wv >> 1;        // PV d-slice (32 d)
  const int ln  = tid & 63;
  const int g   = ln >> 4;
  const int c16 = ln & 15;

  // batch -> XCD-pair remap (context 2MB/batch stays L2-resident under lockstep)
  const int lin   = blockIdx.y * 64 + blockIdx.x;
  const int b     = (lin & 7) >> 1;
  const int otile = ((lin >> 3) << 1) | (lin & 1);
  const int o0    = otile * 64;
  const int bo    = b * LSEQ + o0;

  const _Float16* __restrict__ cbase = cT16 + (size_t)b * LSEQ * DDIM;
  const _Float16* __restrict__ cDb   = cD16 + (size_t)b * DDIM * LSEQ;

  // B-frags: o = ow*16 + c16, k = kk*32 + g*8..
  f16x8 qb[8];
#pragma unroll
  for (int kk = 0; kk < 8; ++kk)
    qb[kk] = *(const f16x8*)(qw16 +
        ((size_t)(bo + ow * 16 + c16) << 8) + kk * 32 + g * 8);

  auto issue_dma = [&](int t, int pp) {
#pragma unroll
    for (int i = 0; i < 2; ++i) {
      unsigned x  = (unsigned)tid * 16 + i * 16384;
      unsigned q  = x >> 9;
      unsigned db = (x & 511u) ^ ((q & 7u) << 4);
      gld16(cbase + ((size_t)(t * TQ + q) << 8) + (db >> 1), &smem[pp][x]);
    }
  };

  auto scores = [&](const char* cl) {
    f32x4 sa{0.f, 0.f, 0.f, 0.f};
#pragma unroll
    for (int kk = 0; kk < 8; ++kk) {
      unsigned off = (unsigned)((qw * 16 + c16) * 512 + kk * 64 + g * 16) ^
                     ((unsigned)(c16 & 7) << 4);
      f16x8 af = *(const f16x8*)(cl + off);
      sa = __builtin_amdgcn_mfma_f32_16x16x32_f16(af, qb[kk], sa, 0, 0, 0);
    }
    return sa;
  };

  const int o_mine = ow * 16 + c16;

  // exp + wgt-store + wbuf-write for tile t (sa already computed)
  auto emit_w = [&](const f32x4& sa, int q0, float invl) {
    f32x4 wv4;
    f16x4 wh;
#pragma unroll
    for (int r = 0; r < 4; ++r) {
      float w = __expf(sa[r]) * invl;
      wv4[r] = w;
      wh[r]  = (_Float16)w;
    }
    *(f32x4*)(wgt + ((size_t)(bo + o_mine) << 12) + q0 + qw * 16 + 4 * g) = wv4;
    unsigned wb = (unsigned)(o_mine * 128 + (qw * 16 + 4 * g) * 2) ^
                  ((unsigned)(o_mine & 7) << 4);
    *(f16x4*)(wbuf + wb) = wh;
  };

  // ---- phase A: staged scores, lsum += exp(s) (r10 verbatim) ----
  float ls = 0.f;
  int p = 0;
  issue_dma(0, 0);
  for (int t = 0; t < LSEQ / TQ; ++t) {
    asm volatile("s_waitcnt vmcnt(0)" ::: "memory");
    __builtin_amdgcn_s_barrier();
    issue_dma(t < LSEQ / TQ - 1 ? t + 1 : 0, p ^ 1);  // t=63 stages B's tile 0
    __builtin_amdgcn_sched_barrier(0);

    f32x4 sa = scores(smem[p]);
#pragma unroll
    for (int r = 0; r < 4; ++r) ls += __expf(sa[r]);
    p ^= 1;
  }

  ls += __shfl_xor(ls, 16);
  ls += __shfl_xor(ls, 32);
  if (ln < 16) redbuf[qw][ow * 16 + ln] = ls;
  __syncthreads();
  const float invl = 1.0f / (redbuf[0][o_mine] + redbuf[1][o_mine] +
                             redbuf[2][o_mine] + redbuf[3][o_mine]);

  // ---- phase B (pipelined): scores(t+1) ∥ PV(t) ----
  f32x4 oacc[4][2];
#pragma unroll
  for (int m = 0; m < 4; ++m)
#pragma unroll
    for (int nf = 0; nf < 2; ++nf) oacc[m][nf] = f32x4{0.f, 0.f, 0.f, 0.f};

  // B prologue: tile 0 scores + w-emit (p==0 holds tile 0 after phase A)
  asm volatile("s_waitcnt vmcnt(0)" ::: "memory");
  __builtin_amdgcn_s_barrier();
  issue_dma(1, p ^ 1);
  __builtin_amdgcn_sched_barrier(0);
  {
    f32x4 sa = scores(smem[p]);
    emit_w(sa, 0, invl);
  }
  asm volatile("s_waitcnt lgkmcnt(0)" ::: "memory");
  __builtin_amdgcn_sched_barrier(0);

  for (int t = 0; t < LSEQ / TQ - 1; ++t) {
    // wait DMA(t+1) (2 loads); 1 newer wgt store may still fly
    asm volatile("s_waitcnt vmcnt(1)" ::: "memory");
    __builtin_amdgcn_s_barrier();   // wbuf(t) + c_lds(t+1) visible
    __builtin_amdgcn_sched_barrier(0);
    if (t + 2 <= LSEQ / TQ - 1) issue_dma(t + 2, p);

    // PV(t) B-frags from L2-hot cD16
    const int q0 = t * TQ;
    f16x8 bv[2];
#pragma unroll
    for (int nf = 0; nf < 2; ++nf)
      bv[nf] = *(const f16x8*)(cDb +
          ((size_t)(dw * 32 + nf * 16 + c16) << 12) + q0 + kh * 32 + g * 8);

    // scores(t+1) ∥ PV(t): independent streams, one barrier interval
    f32x4 sa = scores(smem[p ^ 1]);
#pragma unroll
    for (int m = 0; m < 4; ++m) {
      unsigned off = (unsigned)((m * 16 + c16) * 128 + kh * 64 + g * 16) ^
                     ((unsigned)(c16 & 7) << 4);
      f16x8 wa = *(const f16x8*)(wbuf + off);
#pragma unroll
      for (int nf = 0; nf < 2; ++nf)
        oacc[m][nf] =
            __builtin_amdgcn_mfma_f32_16x16x32_f16(wa, bv[nf], oacc[m][nf], 0, 0, 0);
    }
    asm volatile("s_waitcnt lgkmcnt(0)" ::: "memory");
    __builtin_amdgcn_s_barrier();   // all PV(t) wbuf reads done
    __builtin_amdgcn_sched_barrier(0);

    // thin interval: exp + stores for tile t+1
    emit_w(sa, (t + 1) * TQ, invl);
    asm volatile("s_waitcnt lgkmcnt(0)" ::: "memory");
    __builtin_amdgcn_sched_barrier(0);
    p ^= 1;
  }

  // tail: PV(63)
  __builtin_amdgcn_s_barrier();     // wbuf(63) visible
  __builtin_amdgcn_sched_barrier(0);
  {
    const int q0 = (LSEQ / TQ - 1) * TQ;
    f16x8 bv[2];
#pragma unroll
    for (int nf = 0; nf < 2; ++nf)
      bv[nf] = *(const f16x8*)(cDb +
          ((size_t)(dw * 32 + nf * 16 + c16) << 12) + q0 + kh * 32 + g * 8);
#pragma unroll
    for (int m = 0; m < 4; ++m) {
      unsigned off = (unsigned)((m * 16 + c16) * 128 + kh * 64 + g * 16) ^
                     ((unsigned)(c16 & 7) << 4);
      f16x8 wa = *(const f16x8*)(wbuf + off);
#pragma unroll
      for (int nf = 0; nf < 2; ++nf)
        oacc[m][nf] =
            __builtin_amdgcn_mfma_f32_16x16x32_f16(wa, bv[nf], oacc[m][nf], 0, 0, 0);
    }
  }

  // ---- cross-kh reduction via obuf (smem dead), then store out
  __syncthreads();
  if (kh == 1) {
#pragma unroll
    for (int m = 0; m < 4; ++m)
#pragma unroll
      for (int nf = 0; nf < 2; ++nf)
        *(f32x4*)(obuf + dw * 8192 + (m * 2 + nf) * 1024 + ln * 16) = oacc[m][nf];
  }
  __syncthreads();
  if (kh == 0) {
#pragma unroll
    for (int m = 0; m < 4; ++m)
#pragma unroll
      for (int nf = 0; nf < 2; ++nf) {
        f32x4 o2 = *(const f32x4*)(obuf + dw * 8192 + (m * 2 + nf) * 1024 + ln * 16);
        f32x4 o  = oacc[m][nf] + o2;
#pragma unroll
        for (int r = 0; r < 4; ++r)
          outp[((size_t)(bo + m * 16 + 4 * g + r) << 8) + dw * 32 + nf * 16 + c16] = o[r];
      }
  }
}

extern "C" void kernel_launch(void* const* d_in, const int* in_sizes, int n_in,
                              void* d_out, int out_size, void* d_ws, size_t ws_size,
                              hipStream_t stream) {
  const float* query   = (const float*)d_in[0];
  const float* context = (const float*)d_in[1];
  const float* W_in    = (const float*)d_in[2];
  const float* b_in    = (const float*)d_in[3];

  float* outp = (float*)d_out;
  float* wgt  = outp + (size_t)BATCH * LSEQ * DDIM;  // outputs concat: out, weights

  const size_t NELEM = (size_t)BATCH * LSEQ * DDIM;  // 4,194,304
  _Float16* qT16 = (_Float16*)d_ws;
  _Float16* cT16 = qT16 + NELEM;
  _Float16* qw16 = cT16 + NELEM;
  _Float16* W16  = qw16 + NELEM;   // +65536 halfs
  _Float16* cD16 = W16 + 65536;    // context f16, [B][D][L]; total ws ~33.7 MB

  transpose_cast<<<dim3(LSEQ / 64, DDIM / 64, 2 * BATCH), 256, 0, stream>>>(
      query, context, qT16, cT16, cD16);
  wconv<<<(DDIM * DDIM) / 1024, 256, 0, stream>>>(W_in, W16);
  linear_q<<<(BATCH * LSEQ) / 64, 256, 0, stream>>>(qT16, W16, b_in, qw16);
  attn_main<<<dim3(64, BATCH), 1024, 0, stream>>>(qw16, cT16, cD16, outp, wgt);
}

// Round 17
// 292.539 us; speedup vs baseline: 1.1473x; 1.0003x over previous
//
#include <hip/hip_runtime.h>

// Luong 'general' attention, B=4 D=256 L=4096.
// K0 transpose/cast q,c -> [B][L][D] f16 (+ cB16 [B][D][L] bf16 context);
// K0b W f32->f16 ; K1 linear qw=q@W^T+b.
// K2 attn_main: SINGLE flash-style pass (256 blocks lockstep, 16 waves, TQ=64):
//   scores once from DMA-staged c_lds; u=exp(s) -> bf16 u16 ws (raw, e^40 fits
//   bf16; f16 overflows at 2.2sigma) + bf16 wbuf; PV accumulates UNNORMALIZED
//   (bf16 MFMA, B from L2-hot cB16); epilogue: out = oacc*invl, invl_tab out.
//   This deletes r9/r10's phase A (64 staged iterations) entirely.
// K3 normalize_w: pure streaming wgt = u16 * invl_tab[row] (134MB r + 268MB w).
// LDS: 2x32KB c_lds + 8KB wbuf + 1KB redbuf + 256B invbuf (obuf aliases smem).
// ws: ~168 MB (poison fill shows ws >= ~850 MB).

#define BATCH 4
#define DDIM  256
#define LSEQ  4096
#define TQ    64

typedef float    f32x4 __attribute__((ext_vector_type(4)));
typedef _Float16 f16x8 __attribute__((ext_vector_type(8)));
typedef _Float16 f16x4 __attribute__((ext_vector_type(4)));
typedef short    b16x8 __attribute__((ext_vector_type(8)));
typedef short    b16x4 __attribute__((ext_vector_type(4)));
typedef unsigned short u16x8 __attribute__((ext_vector_type(8)));

__device__ __forceinline__ void gld16(const void* g, void* l) {
  __builtin_amdgcn_global_load_lds((const __attribute__((address_space(1))) void*)g,
                                   (__attribute__((address_space(3))) void*)l, 16, 0, 0);
}

__device__ __forceinline__ short f2bf(float f) {  // RNE f32 -> bf16
  unsigned u = __builtin_bit_cast(unsigned, f);
  return (short)((u + 0x7FFFu + ((u >> 16) & 1u)) >> 16);
}

// ---------------- K0: [B][D][L] f32 -> [B][L][D] f16 (+ cB16 bf16 [B][D][L]) -
__global__ __launch_bounds__(256) void transpose_cast(
    const float* __restrict__ q_in, const float* __restrict__ c_in,
    _Float16* __restrict__ q_out, _Float16* __restrict__ c_out,
    short* __restrict__ cB16)
{
  __shared__ float tile[64][68];
  const int which = blockIdx.z >> 2;
  const int b     = blockIdx.z & 3;
  const float* __restrict__ src = which ? c_in : q_in;
  _Float16* __restrict__ dst    = which ? c_out : q_out;
  const int l0 = blockIdx.x * 64, d0 = blockIdx.y * 64;
  const int tid = threadIdx.x;
  const int tr = tid >> 4, tc = (tid & 15) << 2;
#pragma unroll
  for (int i = 0; i < 4; ++i) {
    int d = tr + i * 16;
    f32x4 v = *(const f32x4*)(src + ((size_t)b * DDIM + d0 + d) * LSEQ + l0 + tc);
    *(f32x4*)&tile[d][tc] = v;
    if (which) {
      b16x4 h;
      h[0] = f2bf(v[0]); h[1] = f2bf(v[1]);
      h[2] = f2bf(v[2]); h[3] = f2bf(v[3]);
      *(b16x4*)(cB16 + ((size_t)b * DDIM + d0 + d) * LSEQ + l0 + tc) = h;
    }
  }
  __syncthreads();
#pragma unroll
  for (int i = 0; i < 4; ++i) {
    int l = tr + i * 16;
    f16x4 h;
    h[0] = (_Float16)tile[tc + 0][l];
    h[1] = (_Float16)tile[tc + 1][l];
    h[2] = (_Float16)tile[tc + 2][l];
    h[3] = (_Float16)tile[tc + 3][l];
    *(f16x4*)(dst + ((size_t)b * LSEQ + l0 + l) * DDIM + d0 + tc) = h;
  }
}

// ---------------- K0b: W f32 -> f16 -----------------------------------------
__global__ __launch_bounds__(256) void wconv(const float* __restrict__ w,
                                             _Float16* __restrict__ w16) {
  int i = (blockIdx.x * 256 + threadIdx.x) * 4;
  f32x4 v = *(const f32x4*)(w + i);
  f16x4 h;
  h[0] = (_Float16)v[0]; h[1] = (_Float16)v[1];
  h[2] = (_Float16)v[2]; h[3] = (_Float16)v[3];
  *(f16x4*)(w16 + i) = h;
}

// ---------------- K1: qw16 = qT16 @ W^T + bias ------------------------------
__global__ __launch_bounds__(256) void linear_q(
    const _Float16* __restrict__ qT16, const _Float16* __restrict__ W16,
    const float* __restrict__ bias, _Float16* __restrict__ qw16)
{
  const int tid = threadIdx.x;
  const int wv = tid >> 6, ln = tid & 63, g = ln >> 4, c16 = ln & 15;
  const size_t r0 = (size_t)blockIdx.x * 64 + wv * 16;

  f16x8 qa[8];
  const _Float16* qrow = qT16 + (r0 + c16) * DDIM + g * 8;
#pragma unroll
  for (int kk = 0; kk < 8; ++kk) qa[kk] = *(const f16x8*)(qrow + kk * 32);

  f32x4 acc[16];
#pragma unroll
  for (int n = 0; n < 16; ++n) acc[n] = f32x4{0.f, 0.f, 0.f, 0.f};

#pragma unroll 2
  for (int kk = 0; kk < 8; ++kk) {
#pragma unroll
    for (int n = 0; n < 16; ++n) {
      f16x8 bf = *(const f16x8*)(W16 + (n * 16 + c16) * DDIM + kk * 32 + g * 8);
      acc[n] = __builtin_amdgcn_mfma_f32_16x16x32_f16(qa[kk], bf, acc[n], 0, 0, 0);
    }
  }
#pragma unroll
  for (int n = 0; n < 16; ++n) {
    float bb = bias[n * 16 + c16];
#pragma unroll
    for (int r = 0; r < 4; ++r)
      qw16[(r0 + 4 * g + r) * DDIM + n * 16 + c16] = (_Float16)(acc[n][r] + bb);
  }
}

// ---------------- K2: single-pass fused attention (16 waves) ----------------
// c_lds (q-major): byte = q*512 + d*2 ^ ((q&7)<<4); scores-A read b128:
//   off=(qw*16+c16)*512+kk*64+g*16 ^ ((c16&7)<<4).
// wbuf [64 o][64 q] bf16: byte = o*128 + q*2 ^ ((o&7)<<4); write b16x4, read b128.
// DMA: linear LDS dest + inverse-swizzled global source (rule #21).
__global__ __launch_bounds__(1024, 4) void attn_main(
    const _Float16* __restrict__ qw16,
    const _Float16* __restrict__ cT16,
    const short* __restrict__ cB16,
    float* __restrict__ outp,
    unsigned short* __restrict__ u16g,
    float* __restrict__ invl_tab)
{
  __shared__ __align__(16) char smem[2][32768];  // c_lds double buffer
  __shared__ __align__(16) char wbuf[8192];      // u tile [64 o][64 q] bf16 swz
  __shared__ float redbuf[4][64];                // per-qw row sums
  __shared__ float invbuf[64];                   // 1/lsum per o
  char* obuf = &smem[0][0];                      // epilogue alias (64KB, dead)

  const int tid = threadIdx.x;
  const int wv  = tid >> 6;       // 0..15
  const int qw  = wv & 3;         // scores q-frag
  const int ow  = wv >> 2;        // scores o-frag (16 o each)
  const int kh  = wv & 1;         // PV k-half (32 q)
  const int dw  = wv >> 1;        // PV d-slice (32 d)
  const int ln  = tid & 63;
  const int g   = ln >> 4;
  const int c16 = ln & 15;

  // batch -> XCD-pair remap (context 2MB/batch stays L2-resident under lockstep)
  const int lin   = blockIdx.y * 64 + blockIdx.x;
  const int b     = (lin & 7) >> 1;
  const int otile = ((lin >> 3) << 1) | (lin & 1);
  const int o0    = otile * 64;
  const int bo    = b * LSEQ + o0;

  const _Float16* __restrict__ cbase = cT16 + (size_t)b * LSEQ * DDIM;
  const short* __restrict__ cBb      = cB16 + (size_t)b * DDIM * LSEQ;

  // scores B-frags: o = ow*16 + c16, k = kk*32 + g*8..
  f16x8 qb[8];
#pragma unroll
  for (int kk = 0; kk < 8; ++kk)
    qb[kk] = *(const f16x8*)(qw16 +
        ((size_t)(bo + ow * 16 + c16) << 8) + kk * 32 + g * 8);

  auto issue_dma = [&](int t, int pp) {
#pragma unroll
    for (int i = 0; i < 2; ++i) {
      unsigned x  = (unsigned)tid * 16 + i * 16384;
      unsigned q  = x >> 9;
      unsigned db = (x & 511u) ^ ((q & 7u) << 4);
      gld16(cbase + ((size_t)(t * TQ + q) << 8) + (db >> 1), &smem[pp][x]);
    }
  };

  auto scores = [&](const char* cl) {
    f32x4 sa{0.f, 0.f, 0.f, 0.f};
#pragma unroll
    for (int kk = 0; kk < 8; ++kk) {
      unsigned off = (unsigned)((qw * 16 + c16) * 512 + kk * 64 + g * 16) ^
                     ((unsigned)(c16 & 7) << 4);
      f16x8 af = *(const f16x8*)(cl + off);
      sa = __builtin_amdgcn_mfma_f32_16x16x32_f16(af, qb[kk], sa, 0, 0, 0);
    }
    return sa;
  };

  const int o_mine = ow * 16 + c16;

  // ---- single pass: scores -> u=exp(s) -> {u16 ws, wbuf} -> unnormalized PV
  float ls = 0.f;
  f32x4 oacc[4][2];
#pragma unroll
  for (int m = 0; m < 4; ++m)
#pragma unroll
    for (int nf = 0; nf < 2; ++nf) oacc[m][nf] = f32x4{0.f, 0.f, 0.f, 0.f};

  int p = 0;
  issue_dma(0, 0);
  for (int t = 0; t < LSEQ / TQ; ++t) {
    const int q0 = t * TQ;
    if (t == 0) asm volatile("s_waitcnt vmcnt(0)" ::: "memory");
    else        asm volatile("s_waitcnt vmcnt(1)" ::: "memory");
    __builtin_amdgcn_s_barrier();
    __builtin_amdgcn_sched_barrier(0);

    // PV B-frags from L2-hot cB16 (bf16)
    b16x8 bv[2];
#pragma unroll
    for (int nf = 0; nf < 2; ++nf)
      bv[nf] = *(const b16x8*)(cBb +
          ((size_t)(dw * 32 + nf * 16 + c16) << 12) + q0 + kh * 32 + g * 8);

    if (t < LSEQ / TQ - 1) issue_dma(t + 1, p ^ 1);

    f32x4 sa = scores(smem[p]);

    // u = exp(s): lsum, raw-bf16 to ws + wbuf
    {
      b16x4 uh;
#pragma unroll
      for (int r = 0; r < 4; ++r) {
        float u = __expf(sa[r]);
        ls += u;
        uh[r] = f2bf(u);
      }
      *(b16x4*)(u16g + ((size_t)(bo + o_mine) << 12) + q0 + qw * 16 + 4 * g) =
          *(b16x4*)&uh;
      unsigned wb = (unsigned)(o_mine * 128 + (qw * 16 + 4 * g) * 2) ^
                    ((unsigned)(o_mine & 7) << 4);
      *(b16x4*)(wbuf + wb) = uh;
    }
    asm volatile("s_waitcnt lgkmcnt(0)" ::: "memory");
    __builtin_amdgcn_s_barrier();
    __builtin_amdgcn_sched_barrier(0);

    // PV: A = wbuf rows (o), k-half kh; B = bv; out d-slice dw  (bf16 MFMA)
#pragma unroll
    for (int m = 0; m < 4; ++m) {
      unsigned off = (unsigned)((m * 16 + c16) * 128 + kh * 64 + g * 16) ^
                     ((unsigned)(c16 & 7) << 4);
      b16x8 wa = *(const b16x8*)(wbuf + off);
#pragma unroll
      for (int nf = 0; nf < 2; ++nf)
        oacc[m][nf] =
            __builtin_amdgcn_mfma_f32_16x16x32_bf16(wa, bv[nf], oacc[m][nf], 0, 0, 0);
    }
    p ^= 1;
  }

  // ---- lsum reduce -> invbuf + invl_tab
  ls += __shfl_xor(ls, 16);
  ls += __shfl_xor(ls, 32);
  if (ln < 16) redbuf[qw][ow * 16 + ln] = ls;
  __syncthreads();
  if (tid < 64) {
    float s = redbuf[0][tid] + redbuf[1][tid] + redbuf[2][tid] + redbuf[3][tid];
    float iv = 1.0f / s;
    invbuf[tid] = iv;
    invl_tab[bo + tid] = iv;
  }
  __syncthreads();

  // ---- cross-kh reduction via obuf (smem dead), scale by invl, store out
  if (kh == 1) {
#pragma unroll
    for (int m = 0; m < 4; ++m)
#pragma unroll
      for (int nf = 0; nf < 2; ++nf)
        *(f32x4*)(obuf + dw * 8192 + (m * 2 + nf) * 1024 + ln * 16) = oacc[m][nf];
  }
  __syncthreads();
  if (kh == 0) {
#pragma unroll
    for (int m = 0; m < 4; ++m)
#pragma unroll
      for (int nf = 0; nf < 2; ++nf) {
        f32x4 o2 = *(const f32x4*)(obuf + dw * 8192 + (m * 2 + nf) * 1024 + ln * 16);
        f32x4 o  = oacc[m][nf] + o2;
#pragma unroll
        for (int r = 0; r < 4; ++r) {
          float iv = invbuf[m * 16 + 4 * g + r];
          outp[((size_t)(bo + m * 16 + 4 * g + r) << 8) + dw * 32 + nf * 16 + c16] =
              o[r] * iv;
        }
      }
  }
}

// ---------------- K3: wgt = u16 * invl[row] (pure streaming) ----------------
__global__ __launch_bounds__(256) void normalize_w(
    const unsigned short* __restrict__ u16g,
    const float* __restrict__ invl_tab,
    float* __restrict__ wgt)
{
  const size_t N = (size_t)BATCH * LSEQ * LSEQ;
  const size_t stride = (size_t)gridDim.x * 256 * 8;
  for (size_t i = ((size_t)blockIdx.x * 256 + threadIdx.x) * 8; i < N; i += stride) {
    u16x8 v = *(const u16x8*)(u16g + i);
    float iv = invl_tab[i >> 12];  // row = i / 4096 (8-elem chunk never straddles)
    f32x4 w0, w1;
#pragma unroll
    for (int j = 0; j < 4; ++j) {
      w0[j] = __builtin_bit_cast(float, (unsigned)v[j] << 16) * iv;
      w1[j] = __builtin_bit_cast(float, (unsigned)v[4 + j] << 16) * iv;
    }
    *(f32x4*)(wgt + i)     = w0;
    *(f32x4*)(wgt + i + 4) = w1;
  }
}

extern "C" void kernel_launch(void* const* d_in, const int* in_sizes, int n_in,
                              void* d_out, int out_size, void* d_ws, size_t ws_size,
                              hipStream_t stream) {
  const float* query   = (const float*)d_in[0];
  const float* context = (const float*)d_in[1];
  const float* W_in    = (const float*)d_in[2];
  const float* b_in    = (const float*)d_in[3];

  float* outp = (float*)d_out;
  float* wgt  = outp + (size_t)BATCH * LSEQ * DDIM;  // outputs concat: out, weights

  const size_t NELEM = (size_t)BATCH * LSEQ * DDIM;  // 4,194,304
  _Float16* qT16 = (_Float16*)d_ws;
  _Float16* cT16 = qT16 + NELEM;
  _Float16* qw16 = cT16 + NELEM;
  _Float16* W16  = qw16 + NELEM;                   // +65536 halfs
  short*    cB16 = (short*)(W16 + 65536);          // bf16 context [B][D][L]
  float*    invl_tab = (float*)(cB16 + NELEM);     // B*L f32 = 64 KB
  unsigned short* u16g = (unsigned short*)(invl_tab + (size_t)BATCH * LSEQ);
  // u16g: B*L*L bf16 = 134 MB; total ws ~168 MB (ws_size ~0.85+ GB per fills)

  transpose_cast<<<dim3(LSEQ / 64, DDIM / 64, 2 * BATCH), 256, 0, stream>>>(
      query, context, qT16, cT16, cB16);
  wconv<<<(DDIM * DDIM) / 1024, 256, 0, stream>>>(W_in, W16);
  linear_q<<<(BATCH * LSEQ) / 64, 256, 0, stream>>>(qT16, W16, b_in, qw16);
  attn_main<<<dim3(64, BATCH), 1024, 0, stream>>>(qw16, cT16, cB16, outp, u16g,
                                                  invl_tab);
  normalize_w<<<2048, 256, 0, stream>>>(u16g, invl_tab, wgt);
}